// Round 14
// baseline (339.000 us; speedup 1.0000x reference)
//
#include <hip/hip_runtime.h>
#include <hip/hip_bf16.h>

#define NB 32
#define SS 1024
#define DD 768

typedef __attribute__((ext_vector_type(8))) short bf16x8;
typedef __attribute__((ext_vector_type(4))) float f32x4;

__device__ inline ushort f2bf(float f) {
    union { float f; unsigned u; } x;
    x.f = f;
    unsigned r = (x.u + 0x7fffu + ((x.u >> 16) & 1u)) >> 16;
    return (ushort)r;
}

__device__ inline float bf2f(ushort u) {
    union { unsigned u; float f; } x;
    x.u = ((unsigned)u) << 16;
    return x.f;
}

#define GLOBAL_PTR(x) ((const __attribute__((address_space(1))) void*)(x))
#define LDS_PTR(x)    ((__attribute__((address_space(3))) void*)(x))

// ---------------------------------------------------------------- K0: gather x = bf16(emb[tokens]) + convert wq/wk -> bf16
__global__ void k_prep(const int* __restrict__ tokens, const float* __restrict__ emb,
                       const float* __restrict__ wq, const float* __restrict__ wk,
                       ushort* __restrict__ xb, ushort* __restrict__ wqb, ushort* __restrict__ wkb) {
    const int bid = blockIdx.x;
    if (bid < 24576) {
        int i = (bid * 256 + threadIdx.x) * 4;
        int row = i / DD;
        int col = i - row * DD;
        int tok = tokens[row];
        const float4 v = *(const float4*)(emb + (size_t)tok * DD + col);
        ushort4 o;
        o.x = f2bf(v.x); o.y = f2bf(v.y); o.z = f2bf(v.z); o.w = f2bf(v.w);
        *(ushort4*)(xb + (size_t)row * DD + col) = o;
    } else {
        const int b2 = bid - 24576;
        const float* src = (b2 < 576) ? wq : wk;
        ushort* dst = (b2 < 576) ? wqb : wkb;
        const int local = (b2 < 576) ? b2 : b2 - 576;
        const int i = (local * 256 + threadIdx.x) * 4;
        const float4 v = *(const float4*)(src + i);
        ushort4 o;
        o.x = f2bf(v.x); o.y = f2bf(v.y); o.z = f2bf(v.z); o.w = f2bf(v.w);
        *(ushort4*)(dst + i) = o;
    }
}

// ---------------------------------------------------------------- 128x128 GEMM (m97 structure, dbuf): C = A@Bt^T, bf16 out
__global__ __launch_bounds__(256, 2) void k_gemm_s(const ushort* __restrict__ A,
                                                   const ushort* __restrict__ Bt,
                                                   ushort* __restrict__ Cb) {
    constexpr int BK = 64;
    __shared__ ushort As[2][128 * BK];
    __shared__ ushort Bs[2][128 * BK];
    const int tid = threadIdx.x;
    const int wave = tid >> 6, lane = tid & 63;
    const int bx = blockIdx.x, by = blockIdx.y;
    const size_t abase = (size_t)bx * 128 * DD;
    const size_t bbase = (size_t)by * 128 * DD;
    const int r = tid >> 3;
    const int cc = (tid & 7) * 8;

    auto stage = [&](int buf, int k0) {
#pragma unroll
        for (int i = 0; i < 4; i++) {
            __builtin_amdgcn_global_load_lds(GLOBAL_PTR(A + abase + (size_t)(r + i * 32) * DD + k0 + cc),
                                             LDS_PTR(&As[buf][(r + i * 32) * BK + cc]), 16, 0, 0);
            __builtin_amdgcn_global_load_lds(GLOBAL_PTR(Bt + bbase + (size_t)(r + i * 32) * DD + k0 + cc),
                                             LDS_PTR(&Bs[buf][(r + i * 32) * BK + cc]), 16, 0, 0);
        }
    };

    f32x4 acc[4][4] = {};
    const int wm = (wave >> 1) * 64, wn = (wave & 1) * 64;
    const int lr = lane & 15, lc = (lane >> 4) * 8;

    stage(0, 0);
    __syncthreads();
    int cur = 0;
#pragma unroll 1
    for (int k0 = 0; k0 < DD; k0 += BK) {
        if (k0 + BK < DD) stage(cur ^ 1, k0 + BK);
        const ushort* as = As[cur];
        const ushort* bs = Bs[cur];
#pragma unroll
        for (int kk = 0; kk < 2; kk++) {
            bf16x8 af[4], bfv[4];
#pragma unroll
            for (int m = 0; m < 4; m++)
                af[m] = *(const bf16x8*)(as + (wm + m * 16 + lr) * BK + kk * 32 + lc);
#pragma unroll
            for (int n = 0; n < 4; n++)
                bfv[n] = *(const bf16x8*)(bs + (wn + n * 16 + lr) * BK + kk * 32 + lc);
#pragma unroll
            for (int m = 0; m < 4; m++)
#pragma unroll
                for (int n = 0; n < 4; n++)
                    acc[m][n] = __builtin_amdgcn_mfma_f32_16x16x32_bf16(af[m], bfv[n], acc[m][n], 0, 0, 0);
        }
        __syncthreads();
        cur ^= 1;
    }
    const int rowbase = bx * 128 + wm + (lane >> 4) * 4;
    const int colbase = by * 128 + wn + (lane & 15);
#pragma unroll
    for (int m = 0; m < 4; m++)
#pragma unroll
        for (int n = 0; n < 4; n++)
#pragma unroll
            for (int j = 0; j < 4; j++)
                Cb[(size_t)(rowbase + m * 16 + j) * DD + colbase + n * 16] = f2bf(acc[m][n][j]);
}

// ---------------------------------------------------------------- 256x256 batched QK^T, 3-buffer BK=32 counted-vmcnt pipeline.
// Per tile: vmcnt(4) (tile t's 4 loads; t+1's stay in flight) -> s_barrier ->
// stage(t+2) into buffer freed by t-1 -> 12 ds_read_b128 + 32 MFMA. One barrier
// and ZERO full drains per tile (except last). Output: bf16 s interleaved into
// the f32 a-region (first 2KB of each row's 4KB slot; row stride 2048 ushorts).
#define NT 24
__global__ __launch_bounds__(512) void k_gemm256b(const ushort* __restrict__ A,
                                                  const ushort* __restrict__ Bt,
                                                  ushort* __restrict__ Cu) {
    __shared__ ushort Ab[3][256 * 32];   // 3 x 16 KB
    __shared__ ushort Bb[3][256 * 32];   // 3 x 16 KB  -> 96 KB total
    const int tid = threadIdx.x;
    const int wid = tid >> 6, lane = tid & 63;
    const int wm = wid >> 2, wn = wid & 3;
    const int la = lane & 15, lg = lane >> 4;

    const int wgid = blockIdx.x;
    const int g = wgid >> 7, w = wgid & 127;
    const int b = g * 8 + (w & 7);
    const int tile = w >> 3;
    const int bx = tile & 3, by = tile >> 2;
    const ushort* Ag = A + (size_t)b * SS * DD + (size_t)bx * 256 * DD;
    const ushort* Bg = Bt + (size_t)b * SS * DD + (size_t)by * 256 * DD;
    Cu += (size_t)b * SS * 2048;

    // staging: 2 chunks/thread/operand; linear LDS dest, pre-swizzled source.
    // 64B rows (32 bf16); chunk c of row r holds source chunk c ^ ((r>>1)&3).
    int st_r[2], st_c[2], st_d[2];
#pragma unroll
    for (int l = 0; l < 2; l++) {
        const int idx = l * 512 + tid;            // 16B-chunk index 0..1023
        const int r = idx >> 2;                   // row 0..255
        const int c = idx & 3;                    // chunk 0..3
        st_r[l] = r;
        st_c[l] = (c ^ ((r >> 1) & 3)) << 3;      // source col (ushorts)
        st_d[l] = idx * 8;                        // dest ushort offset
    }

    auto stage = [&](int bufi, int k0) {
#pragma unroll
        for (int l = 0; l < 2; l++)
            __builtin_amdgcn_global_load_lds(GLOBAL_PTR(Ag + (size_t)st_r[l] * DD + k0 + st_c[l]),
                                             LDS_PTR(&Ab[bufi][0] + st_d[l]), 16, 0, 0);
#pragma unroll
        for (int l = 0; l < 2; l++)
            __builtin_amdgcn_global_load_lds(GLOBAL_PTR(Bg + (size_t)st_r[l] * DD + k0 + st_c[l]),
                                             LDS_PTR(&Bb[bufi][0] + st_d[l]), 16, 0, 0);
    };

    // read-side: global k-chunk lg of row rr lives at chunk lg ^ ((rr>>1)&3);
    // (rr>>1)&3 == (la>>1)&3 for all fragment rows (bases are multiples of 16).
    const int koff = (lg ^ ((la >> 1) & 3)) << 3;

    f32x4 acc[8][4] = {};

    stage(0, 0);
    stage(1, 32);

#pragma unroll 1
    for (int t = 0; t < NT - 1; ++t) {
        asm volatile("s_waitcnt vmcnt(4)" ::: "memory");   // tile t landed; t+1 in flight
        __builtin_amdgcn_sched_barrier(0);
        __builtin_amdgcn_s_barrier();                      // all waves: t landed, t-1 consumed
        if (t + 2 < NT) stage((t + 2) % 3, (t + 2) * 32);  // overwrite t-1's buffer
        const ushort* ab = &Ab[t % 3][0];
        const ushort* bb = &Bb[t % 3][0];
        bf16x8 af[8], bfv[4];
#pragma unroll
        for (int m = 0; m < 8; m++)
            af[m] = *(const bf16x8*)(ab + (wm * 128 + m * 16 + la) * 32 + koff);
#pragma unroll
        for (int n = 0; n < 4; n++)
            bfv[n] = *(const bf16x8*)(bb + (wn * 64 + n * 16 + la) * 32 + koff);
        __builtin_amdgcn_s_setprio(1);
#pragma unroll
        for (int m = 0; m < 8; m++)
#pragma unroll
            for (int n = 0; n < 4; n++)
                acc[m][n] = __builtin_amdgcn_mfma_f32_16x16x32_bf16(af[m], bfv[n], acc[m][n], 0, 0, 0);
        __builtin_amdgcn_s_setprio(0);
    }
    // last tile: full drain (only one in the kernel)
    asm volatile("s_waitcnt vmcnt(0)" ::: "memory");
    __builtin_amdgcn_sched_barrier(0);
    __builtin_amdgcn_s_barrier();
    {
        const ushort* ab = &Ab[(NT - 1) % 3][0];
        const ushort* bb = &Bb[(NT - 1) % 3][0];
        bf16x8 af[8], bfv[4];
#pragma unroll
        for (int m = 0; m < 8; m++)
            af[m] = *(const bf16x8*)(ab + (wm * 128 + m * 16 + la) * 32 + koff);
#pragma unroll
        for (int n = 0; n < 4; n++)
            bfv[n] = *(const bf16x8*)(bb + (wn * 64 + n * 16 + la) * 32 + koff);
        __builtin_amdgcn_s_setprio(1);
#pragma unroll
        for (int m = 0; m < 8; m++)
#pragma unroll
            for (int n = 0; n < 4; n++)
                acc[m][n] = __builtin_amdgcn_mfma_f32_16x16x32_bf16(af[m], bfv[n], acc[m][n], 0, 0, 0);
        __builtin_amdgcn_s_setprio(0);
    }

    const int rowbase = bx * 256 + wm * 128 + (lane >> 4) * 4;
    const int colbase = by * 256 + wn * 64 + la;
#pragma unroll
    for (int m = 0; m < 8; m++)
#pragma unroll
        for (int n = 0; n < 4; n++)
#pragma unroll
            for (int j = 0; j < 4; j++)
                Cu[(size_t)(rowbase + m * 16 + j) * 2048 + colbase + n * 16] = f2bf(acc[m][n][j]);
}

// ---------------------------------------------------------------- masked softmax: one wave per row; reads bf16 s from the
// first 2KB of the row's own 4KB slot, overwrites the full slot with f32 a.
__global__ __launch_bounds__(256) void k_smax(const ushort* __restrict__ su, const int* __restrict__ mask,
                                              float* __restrict__ a) {
    const int tid = threadIdx.x, lane = tid & 63;
    const int row = blockIdx.x * 4 + (tid >> 6);
    const int b = row >> 10;
    const int* mrow = mask + b * SS;
    const ushort* srow = su + (size_t)row * 2048;

    float e[4][4];
    float psum = 0.f;
#pragma unroll
    for (int g = 0; g < 4; g++) {
        const int t = g * 256 + lane * 4;
        const int4 mk = *(const int4*)(mrow + t);
        const ushort4 sv4 = *(const ushort4*)(srow + t);
        e[g][0] = __expf(bf2f(sv4.x) + (mk.x ? -1e9f : 0.0f));
        e[g][1] = __expf(bf2f(sv4.y) + (mk.y ? -1e9f : 0.0f));
        e[g][2] = __expf(bf2f(sv4.z) + (mk.z ? -1e9f : 0.0f));
        e[g][3] = __expf(bf2f(sv4.w) + (mk.w ? -1e9f : 0.0f));
        psum += e[g][0] + e[g][1] + e[g][2] + e[g][3];
    }
#pragma unroll
    for (int off = 32; off; off >>= 1) psum += __shfl_xor(psum, off);
    const float inv = 1.0f / psum;
    float* arow = a + (size_t)row * SS;
#pragma unroll
    for (int g = 0; g < 4; g++) {
        const int t = g * 256 + lane * 4;
        float4 o;
        o.x = e[g][0] * inv; o.y = e[g][1] * inv; o.z = e[g][2] * inv; o.w = e[g][3] * inv;
        *(float4*)(arow + t) = o;
    }
}

// ---------------------------------------------------------------- K4a: partial xbar[b][k] = sum_t a[b,0,t]*emb[tok[b,t]][k]
__global__ __launch_bounds__(256) void k_xbar(const float* __restrict__ a, const int* __restrict__ tokens,
                                              const float* __restrict__ emb, float* __restrict__ part) {
    const int b = blockIdx.x >> 3, c = blockIdx.x & 7;
    __shared__ float a0s[128];
    __shared__ int toks[128];
    const int tid = threadIdx.x;
    if (tid < 128) {
        a0s[tid] = a[(size_t)b * SS * SS + c * 128 + tid];
        toks[tid] = tokens[b * SS + c * 128 + tid];
    }
    __syncthreads();
    float acc0 = 0.f, acc1 = 0.f, acc2 = 0.f;
#pragma unroll 4
    for (int t = 0; t < 128; t++) {
        const float at = a0s[t];
        const float* er = emb + (size_t)toks[t] * DD;
        acc0 = fmaf(at, er[tid], acc0);
        acc1 = fmaf(at, er[tid + 256], acc1);
        acc2 = fmaf(at, er[tid + 512], acc2);
    }
    float* p = part + ((size_t)c * NB + b) * DD;
    p[tid] = acc0; p[tid + 256] = acc1; p[tid + 512] = acc2;
}

// ---------------------------------------------------------------- K5: cls[b][c] = sum_k xbar[b][k] * wv[k][c]
__global__ __launch_bounds__(128) void k_cls(const float* __restrict__ part, const float* __restrict__ wv,
                                             float* __restrict__ cls) {
    const int b = blockIdx.y, tid = threadIdx.x;
    const int c = blockIdx.x * 128 + tid;
    __shared__ float xb[DD];
#pragma unroll
    for (int j = 0; j < 6; j++) {
        const int k = tid + j * 128;
        float s = 0.f;
#pragma unroll
        for (int p = 0; p < 8; p++) s += part[((size_t)p * NB + b) * DD + k];
        xb[k] = s;
    }
    __syncthreads();
    float acc = 0.f;
#pragma unroll 8
    for (int k = 0; k < DD; k++) acc = fmaf(xb[k], wv[(size_t)k * DD + c], acc);
    cls[(size_t)b * DD + c] = acc;
}

// ---------------------------------------------------------------- K7: LN (in-block) + gelu MLP + partial logits. grid (6,32).
__global__ __launch_bounds__(128) void k_mlp(const float* __restrict__ cls, const float* __restrict__ ln_g,
                                             const float* __restrict__ ln_b, const float* __restrict__ w1,
                                             const float* __restrict__ b1, const float* __restrict__ wh,
                                             float* __restrict__ part_l) {
    const int b = blockIdx.y, tid = threadIdx.x;
    __shared__ float h[DD];
    __shared__ float red2[2];
    float v[6];
#pragma unroll
    for (int q = 0; q < 6; q++) v[q] = cls[(size_t)b * DD + tid + q * 128];
    float s = v[0] + v[1] + v[2] + v[3] + v[4] + v[5];
#pragma unroll
    for (int off = 32; off; off >>= 1) s += __shfl_xor(s, off);
    if ((tid & 63) == 0) red2[tid >> 6] = s;
    __syncthreads();
    const float mu = (red2[0] + red2[1]) * (1.0f / DD);
    float dv = 0.f;
#pragma unroll
    for (int q = 0; q < 6; q++) { const float d = v[q] - mu; dv += d * d; }
#pragma unroll
    for (int off = 32; off; off >>= 1) dv += __shfl_xor(dv, off);
    __syncthreads();
    if ((tid & 63) == 0) red2[tid >> 6] = dv;
    __syncthreads();
    const float var = (red2[0] + red2[1]) * (1.0f / DD);
    const float sc = 1.0f / sqrtf(var + 1e-5f);
#pragma unroll
    for (int q = 0; q < 6; q++) {
        const int d = tid + q * 128;
        h[d] = (v[q] - mu) * sc * ln_g[d] + ln_b[d];
    }
    __syncthreads();

    const int j = blockIdx.x * 128 + tid;
    float p = b1[j];
#pragma unroll 8
    for (int d = 0; d < DD; d++) p = fmaf(h[d], w1[(size_t)d * DD + j], p);
    const float g = 0.5f * p * (1.0f + erff(p * 0.70710678118654752f));
    float l0 = g * wh[j * 2 + 0];
    float l1 = g * wh[j * 2 + 1];
#pragma unroll
    for (int off = 32; off; off >>= 1) { l0 += __shfl_xor(l0, off); l1 += __shfl_xor(l1, off); }
    __shared__ float r0[2], r1[2];
    if ((tid & 63) == 0) { r0[tid >> 6] = l0; r1[tid >> 6] = l1; }
    __syncthreads();
    if (tid == 0) {
        part_l[((size_t)b * 6 + blockIdx.x) * 2 + 0] = r0[0] + r0[1];
        part_l[((size_t)b * 6 + blockIdx.x) * 2 + 1] = r1[0] + r1[1];
    }
}

// ---------------------------------------------------------------- K8: final logits reduce
__global__ __launch_bounds__(64) void k_final(const float* __restrict__ part_l, const float* __restrict__ bh,
                                              float* __restrict__ out) {
    const int b = threadIdx.x;
    if (b < NB) {
        float l0 = bh[0], l1 = bh[1];
#pragma unroll
        for (int c = 0; c < 6; c++) {
            l0 += part_l[((size_t)b * 6 + c) * 2 + 0];
            l1 += part_l[((size_t)b * 6 + c) * 2 + 1];
        }
        out[b * 2 + 0] = l0;
        out[b * 2 + 1] = l1;
    }
}

// ----------------------------------------------------------------
extern "C" void kernel_launch(void* const* d_in, const int* in_sizes, int n_in,
                              void* d_out, int out_size, void* d_ws, size_t ws_size,
                              hipStream_t stream) {
    const int*   tokens = (const int*)d_in[0];
    const int*   mask   = (const int*)d_in[1];
    const float* emb    = (const float*)d_in[2];
    const float* wq     = (const float*)d_in[3];
    const float* wk     = (const float*)d_in[4];
    const float* wv     = (const float*)d_in[5];
    const float* ln_g   = (const float*)d_in[6];
    const float* ln_b   = (const float*)d_in[7];
    const float* w1     = (const float*)d_in[8];
    const float* b1     = (const float*)d_in[9];
    const float* wh     = (const float*)d_in[10];
    const float* bh     = (const float*)d_in[11];
    float* out = (float*)d_out;

    char* ws = (char*)d_ws;
    const size_t XB = (size_t)NB * SS * DD * 2;   // 50,331,648 B
    const size_t WB = (size_t)DD * DD * 2;        // 1,179,648 B
    ushort* xb  = (ushort*)ws;                    // x bf16
    ushort* yb  = (ushort*)(ws + XB);             // y = x @ W bf16
    ushort* wqb = (ushort*)(ws + 2 * XB);         // wq bf16
    ushort* wkb = (ushort*)(ws + 2 * XB + WB);    // wk bf16
    ushort* Wt  = (ushort*)(ws + 2 * XB + 2 * WB);// Wt[e][d] = (wq wk^T)[d][e] bf16
    char*   p4  = ws + 2 * XB + 3 * WB;
    float*  part   = (float*)p4;                          // 8*32*768*4
    float*  cls    = (float*)(p4 + 786432);               // 32*768*4
    float*  part_l = (float*)(p4 + 786432 + 98304);       // 32*6*2*4

    float* a_region = out + 64;  // a: B*S*S floats

    k_prep<<<24576 + 1152, 256, 0, stream>>>(tokens, emb, wq, wk, xb, wqb, wkb);
    // Wt = wk @ wq^T  (Wt[e][d] = sum_j wk[e,j] wq[d,j] = W[d,e])
    k_gemm_s<<<dim3(6, 6), 256, 0, stream>>>(wkb, wqb, Wt);
    // y = x @ W  (balanced 1536-block grid, 2 blocks/CU)
    k_gemm_s<<<dim3(256, 6), 256, 0, stream>>>(xb, Wt, yb);
    // s = y @ x^T -> bf16 interleaved into a_region (3-buf counted-vmcnt pipeline)
    k_gemm256b<<<512, 512, 0, stream>>>(yb, xb, (ushort*)a_region);
    // softmax: read own-row bf16, overwrite full row with f32 a
    k_smax<<<8192, 256, 0, stream>>>((const ushort*)a_region, mask, a_region);
    k_xbar<<<256, 256, 0, stream>>>(a_region, tokens, emb, part);
    k_cls<<<dim3(6, NB), 128, 0, stream>>>(part, wv, cls);
    k_mlp<<<dim3(6, NB), 128, 0, stream>>>(cls, ln_g, ln_b, w1, b1, wh, part_l);
    k_final<<<1, 64, 0, stream>>>(part_l, bh, out);
}